// Round 1
// baseline (181.547 us; speedup 1.0000x reference)
//
#include <hip/hip_runtime.h>
#include <math.h>

// Problem constants (from setup_inputs): B=32, C=256, H=W=56, group=4, d=1
constexpr int B_  = 32;
constexpr int C_  = 256;
constexpr int G_  = 4;
constexpr int K_  = 64;          // C/G
constexpr int H_  = 56;
constexpr int W_  = 56;
constexpr int P_  = H_ * W_;     // 3136
constexpr int NB_ = 29;          // min(H/2,W/2)//d + 1
constexpr int BG_ = B_ * G_;     // 128
constexpr int CP_ = C_ * P_;     // 802816
constexpr int N_  = B_ * CP_;    // 25690112
constexpr int N4_ = N_ / 4;      // 6422528

// Radial bin label in RAW (unshifted) coordinates; equals lab[fftshift idx].
__device__ __forceinline__ int lab_of(int p) {
    int h = p / W_, w = p - h * W_;
    int hh = ((h + 28) % 56) - 28;
    int ww = ((w + 28) % 56) - 28;
    int r2 = hh * hh + ww * ww;
    int rf = (int)sqrtf((float)r2);
    while ((rf + 1) * (rf + 1) <= r2) ++rf;   // exact isqrt fixup
    while (rf * rf > r2) --rf;
    if (rf > 28) rf = 28;
    return rf;                                  // d == 1 -> lab = rf
}

// Kernel 1: comp[b,g,p] = mean_k + max_k over the 64 channels of the group.
__global__ __launch_bounds__(256) void comp_kernel(const float* __restrict__ feature,
                                                   float* __restrict__ comp) {
    int i = blockIdx.x * 256 + threadIdx.x;      // over BG_*P_ = 401408 (exact)
    int bg = i / P_, p = i - bg * P_;
    int b = bg >> 2, g = bg & 3;
    const float* base = feature + (b * C_ + g * K_) * P_ + p;
    float sum = 0.f, mx = -INFINITY;
#pragma unroll 8
    for (int k = 0; k < K_; ++k) {
        float v = base[k * P_];
        sum += v;
        mx = fmaxf(mx, v);
    }
    comp[i] = sum * (1.0f / 64.0f) + mx;
}

// Kernel 2: forward 2-D DFT of comp (one block per (b,g)), plus radial-bin
// sums of |spec|.
__global__ __launch_bounds__(256) void fft_fwd_kernel(const float* __restrict__ comp,
                                                      float* __restrict__ spec_re,
                                                      float* __restrict__ spec_im,
                                                      float* __restrict__ sums) {
    int bg = blockIdx.x;
    __shared__ float s_in[P_];
    __shared__ float s_tr[P_], s_ti[P_];
    __shared__ float twc[56], tws[56];
    __shared__ float s_bins[NB_];
    int t = threadIdx.x;
    if (t < 56) {
        float ang = -6.283185307179586f * (float)t / 56.0f;   // e^{-i 2pi t/56}
        twc[t] = cosf(ang);
        tws[t] = sinf(ang);
    }
    if (t < NB_) s_bins[t] = 0.f;
    for (int i = t; i < P_; i += 256) s_in[i] = comp[bg * P_ + i];
    __syncthreads();
    // Row DFT: tmp[h][kw] = sum_w in[h][w] * e^{-2pi i w kw/56}
    for (int i = t; i < P_; i += 256) {
        int h = i / 56, kw = i - h * 56;
        const float* row = &s_in[h * 56];
        float sr = 0.f, si = 0.f;
        int idx = 0;
        for (int w = 0; w < 56; ++w) {
            float v = row[w];
            sr += v * twc[idx];
            si += v * tws[idx];
            idx += kw; if (idx >= 56) idx -= 56;
        }
        s_tr[i] = sr;
        s_ti[i] = si;
    }
    __syncthreads();
    // Col DFT: spec[kh][kw] = sum_h tmp[h][kw] * e^{-2pi i h kh/56}
    for (int i = t; i < P_; i += 256) {
        int kh = i / 56, kw = i - kh * 56;
        float sr = 0.f, si = 0.f;
        int idx = 0;
        for (int h = 0; h < 56; ++h) {
            float ar = s_tr[h * 56 + kw], ai = s_ti[h * 56 + kw];
            float c = twc[idx], s = tws[idx];
            sr += ar * c - ai * s;
            si += ar * s + ai * c;
            idx += kh; if (idx >= 56) idx -= 56;
        }
        spec_re[bg * P_ + i] = sr;
        spec_im[bg * P_ + i] = si;
        float amp = sqrtf(sr * sr + si * si);
        atomicAdd(&s_bins[lab_of(i)], amp);
    }
    __syncthreads();
    if (t < NB_) sums[bg * NB_ + t] = s_bins[t];
}

// Kernel 3: per-(b,g) FC over 29 bins + leaky relu. Counts recomputed (int, exact).
__global__ __launch_bounds__(64) void fc_kernel(const float* __restrict__ sums,
                                                const float* __restrict__ fc_w,
                                                const float* __restrict__ fc_b,
                                                float* __restrict__ att) {
    int bg = blockIdx.x;
    int g = bg & 3;
    __shared__ int s_cnt[NB_];
    __shared__ float s_pool[NB_];
    int t = threadIdx.x;
    if (t < NB_) s_cnt[t] = 0;
    __syncthreads();
    for (int p = t; p < P_; p += 64) atomicAdd(&s_cnt[lab_of(p)], 1);
    __syncthreads();
    if (t < NB_) s_pool[t] = sums[bg * NB_ + t] / (float)s_cnt[t];
    __syncthreads();
    if (t < NB_) {
        float acc = fc_b[g * NB_ + t];
        const float* wrow = &fc_w[(g * NB_ + t) * NB_];   // fc_w[g, m=t, n]
        for (int n = 0; n < NB_; ++n) acc += s_pool[n] * wrow[n];
        att[bg * NB_ + t] = acc >= 0.f ? acc : 0.01f * acc;
    }
}

// Kernel 4: scale spectrum by att[lab], inverse 2-D DFT (real part), per-plane
// min/max.
__global__ __launch_bounds__(256) void fft_inv_kernel(const float* __restrict__ spec_re,
                                                      const float* __restrict__ spec_im,
                                                      const float* __restrict__ att,
                                                      float* __restrict__ nf,
                                                      float* __restrict__ mnmx) {
    int bg = blockIdx.x;
    __shared__ float s_re[P_], s_im[P_];
    __shared__ float s_tr[P_], s_ti[P_];
    __shared__ float twc[56], tws[56];
    __shared__ float s_att[NB_];
    __shared__ float s_mn[256], s_mx[256];
    int t = threadIdx.x;
    if (t < 56) {
        float ang = 6.283185307179586f * (float)t / 56.0f;    // e^{+i 2pi t/56}
        twc[t] = cosf(ang);
        tws[t] = sinf(ang);
    }
    if (t < NB_) s_att[t] = att[bg * NB_ + t];
    __syncthreads();
    for (int i = t; i < P_; i += 256) {
        float a = s_att[lab_of(i)];
        s_re[i] = spec_re[bg * P_ + i] * a;
        s_im[i] = spec_im[bg * P_ + i] * a;
    }
    __syncthreads();
    // Row inverse pass
    for (int i = t; i < P_; i += 256) {
        int h = i / 56, kw = i - h * 56;
        float sr = 0.f, si = 0.f;
        int idx = 0;
        for (int w = 0; w < 56; ++w) {
            float ar = s_re[h * 56 + w], ai = s_im[h * 56 + w];
            float c = twc[idx], s = tws[idx];
            sr += ar * c - ai * s;
            si += ar * s + ai * c;
            idx += kw; if (idx >= 56) idx -= 56;
        }
        s_tr[i] = sr;
        s_ti[i] = si;
    }
    __syncthreads();
    // Col inverse pass — only the real part is needed.
    float lmn = INFINITY, lmx = -INFINITY;
    for (int i = t; i < P_; i += 256) {
        int kh = i / 56, kw = i - kh * 56;
        float sr = 0.f;
        int idx = 0;
        for (int h = 0; h < 56; ++h) {
            sr += s_tr[h * 56 + kw] * twc[idx] - s_ti[h * 56 + kw] * tws[idx];
            idx += kh; if (idx >= 56) idx -= 56;
        }
        float v = sr * (1.0f / (float)P_);
        nf[bg * P_ + i] = v;
        lmn = fminf(lmn, v);
        lmx = fmaxf(lmx, v);
    }
    s_mn[t] = lmn;
    s_mx[t] = lmx;
    __syncthreads();
    for (int off = 128; off > 0; off >>= 1) {
        if (t < off) {
            s_mn[t] = fminf(s_mn[t], s_mn[t + off]);
            s_mx[t] = fmaxf(s_mx[t], s_mx[t + off]);
        }
        __syncthreads();
    }
    if (t == 0) {
        mnmx[bg * 2 + 0] = s_mn[0];
        mnmx[bg * 2 + 1] = s_mx[0];
    }
}

// Kernel 5: out = feature + gamma[c] * feature * attn_map, float4-vectorized.
__global__ __launch_bounds__(256) void final_kernel(const float* __restrict__ feature,
                                                    const float* __restrict__ gamma,
                                                    const float* __restrict__ nf,
                                                    const float* __restrict__ mnmx,
                                                    float* __restrict__ out) {
    int i = blockIdx.x * 256 + threadIdx.x;       // over N4_ (exact)
    int e = i << 2;
    int b = e / CP_;
    int rem = e - b * CP_;
    int c = rem / P_;
    int p = rem - c * P_;
    int bg = (b << 2) | (c >> 6);
    float mn = mnmx[bg * 2 + 0];
    float mx = mnmx[bg * 2 + 1];
    float inv = 1.0f / (mx - mn);
    float4 f = ((const float4*)feature)[i];
    float4 v = *(const float4*)&nf[bg * P_ + p];
    float gam = gamma[c];
    float4 o;
    o.x = f.x + gam * f.x * ((v.x - mn) * inv);
    o.y = f.y + gam * f.y * ((v.y - mn) * inv);
    o.z = f.z + gam * f.z * ((v.z - mn) * inv);
    o.w = f.w + gam * f.w * ((v.w - mn) * inv);
    ((float4*)out)[i] = o;
}

extern "C" void kernel_launch(void* const* d_in, const int* in_sizes, int n_in,
                              void* d_out, int out_size, void* d_ws, size_t ws_size,
                              hipStream_t stream) {
    const float* feature = (const float*)d_in[0];
    const float* gamma   = (const float*)d_in[1];
    const float* fc_w    = (const float*)d_in[2];
    const float* fc_b    = (const float*)d_in[3];
    // d_in[4] = group (4), d_in[5] = d (1): baked in as compile-time constants.

    float* ws      = (float*)d_ws;
    float* comp    = ws;                       // 401408
    float* spec_re = ws + 401408;              // 401408
    float* spec_im = ws + 802816;              // 401408
    float* sums    = ws + 1204224;             // 3712
    float* att     = ws + 1207936;             // 3712
    float* nf      = ws + 1211648;             // 401408
    float* mnmx    = ws + 1613056;             // 256
    float* out     = (float*)d_out;

    comp_kernel   <<<(BG_ * P_) / 256, 256, 0, stream>>>(feature, comp);
    fft_fwd_kernel<<<BG_, 256, 0, stream>>>(comp, spec_re, spec_im, sums);
    fc_kernel     <<<BG_, 64, 0, stream>>>(sums, fc_w, fc_b, att);
    fft_inv_kernel<<<BG_, 256, 0, stream>>>(spec_re, spec_im, att, nf, mnmx);
    final_kernel  <<<N4_ / 256, 256, 0, stream>>>(feature, gamma, nf, mnmx, out);
}

// Round 2
// 100.314 us; speedup vs baseline: 1.8098x; 1.8098x over previous
//
#include <hip/hip_runtime.h>
#include <math.h>

// Problem constants: B=32, C=256, H=W=56, group=4, d=1
constexpr int B_  = 32;
constexpr int C_  = 256;
constexpr int G_  = 4;
constexpr int K_  = 64;
constexpr int P_  = 3136;        // 56*56
constexpr int NB_ = 29;
constexpr int BG_ = 128;         // B*G
constexpr int CP_ = C_ * P_;
constexpr int N_  = B_ * CP_;
constexpr int N4_ = N_ / 4;
constexpr float TWO_PI = 6.283185307179586f;

// Radial bin label in RAW (unshifted) coords, p = kh*56 + kw.
__device__ __forceinline__ int lab_of(int p) {
    int h = p / 56, w = p - h * 56;
    int hh = ((h + 28) % 56) - 28;
    int ww = ((w + 28) % 56) - 28;
    int r2 = hh * hh + ww * ww;
    int rf = (int)sqrtf((float)r2);
    while ((rf + 1) * (rf + 1) <= r2) ++rf;
    while (rf * rf > r2) --rf;
    if (rf > 28) rf = 28;
    return rf;
}

// Ordered-uint key for float atomic min/max.
__device__ __forceinline__ unsigned fkey(float f) {
    unsigned u = __float_as_uint(f);
    return (u & 0x80000000u) ? ~u : (u | 0x80000000u);
}
__device__ __forceinline__ float fdec(unsigned k) {
    return (k & 0x80000000u) ? __uint_as_float(k ^ 0x80000000u) : __uint_as_float(~k);
}

// Init: zero bin sums, set min/max sentinels.
__global__ __launch_bounds__(256) void init_kernel(float* __restrict__ sums,
                                                   unsigned* __restrict__ mnmx) {
    int t = threadIdx.x;
    for (int i = t; i < BG_ * NB_; i += 256) sums[i] = 0.f;
    if (t < BG_) { mnmx[t * 2] = 0xFFFFFFFFu; mnmx[t * 2 + 1] = 0u; }
}

// comp[b,g,p] = mean_k + max_k, float4-vectorized.
__global__ __launch_bounds__(256) void comp_kernel(const float* __restrict__ feature,
                                                   float* __restrict__ comp) {
    int i = blockIdx.x * 256 + threadIdx.x;      // over BG_*784 = 100352 (exact)
    int bg = i / 784, p4 = i - bg * 784;
    int b = bg >> 2, g = bg & 3;
    const float4* base = (const float4*)(feature + (b * C_ + g * K_) * P_) + p4;
    float4 sum = make_float4(0.f, 0.f, 0.f, 0.f);
    float4 mx  = make_float4(-INFINITY, -INFINITY, -INFINITY, -INFINITY);
#pragma unroll 8
    for (int k = 0; k < K_; ++k) {
        float4 v = base[k * 784];
        sum.x += v.x; sum.y += v.y; sum.z += v.z; sum.w += v.w;
        mx.x = fmaxf(mx.x, v.x); mx.y = fmaxf(mx.y, v.y);
        mx.z = fmaxf(mx.z, v.z); mx.w = fmaxf(mx.w, v.w);
    }
    float4 o;
    o.x = sum.x * (1.f/64.f) + mx.x; o.y = sum.y * (1.f/64.f) + mx.y;
    o.z = sum.z * (1.f/64.f) + mx.z; o.w = sum.w * (1.f/64.f) + mx.w;
    ((float4*)comp)[i] = o;
}

// F1: tmpF[bg][kw][h] = sum_w comp[bg][h][w] e^{-2pi i w kw/56}
// block = (bg, 4 rows h). Map: r=t&3 (row), k=t>>2 (kw). Coalesced writes per k.
__global__ __launch_bounds__(256) void dft_f1(const float* __restrict__ comp,
                                              float2* __restrict__ tmpF) {
    int blk = blockIdx.x, bg = blk / 14, r0 = (blk - bg * 14) * 4;
    __shared__ float  sx[4][57];
    __shared__ float2 stw[56];
    int t = threadIdx.x;
    if (t < 56) { float a = -TWO_PI * (float)t / 56.f; stw[t] = make_float2(cosf(a), sinf(a)); }
    if (t < 224) sx[t / 56][t % 56] = comp[bg * P_ + (r0 + t / 56) * 56 + (t % 56)];
    __syncthreads();
    if (t < 224) {
        int r = t & 3, k = t >> 2;
        float sr = 0.f, si = 0.f; int idx = 0;
        for (int j = 0; j < 56; ++j) {
            float v = sx[r][j];
            float2 tw = stw[idx];
            sr = fmaf(v, tw.x, sr); si = fmaf(v, tw.y, si);
            idx += k; if (idx >= 56) idx -= 56;
        }
        tmpF[bg * P_ + k * 56 + (r0 + r)] = make_float2(sr, si);
    }
}

// F2: specS[bg][kw][kh] = sum_h tmpF[bg][kw][h] e^{-2pi i h kh/56}; bin sums of |spec|.
// block = (bg, 4 rows kw). Map: r=t/56 (kw row), k=t%56 (kh). Coalesced writes.
__global__ __launch_bounds__(256) void dft_f2(const float2* __restrict__ tmpF,
                                              float2* __restrict__ specS,
                                              float* __restrict__ sums) {
    int blk = blockIdx.x, bg = blk / 14, r0 = (blk - bg * 14) * 4;
    __shared__ float2 sx[4][57];
    __shared__ float2 stw[56];
    __shared__ float  sbins[NB_];
    int t = threadIdx.x;
    if (t < 56) { float a = -TWO_PI * (float)t / 56.f; stw[t] = make_float2(cosf(a), sinf(a)); }
    if (t < NB_) sbins[t] = 0.f;
    if (t < 224) sx[t / 56][t % 56] = tmpF[bg * P_ + (r0 + t / 56) * 56 + (t % 56)];
    __syncthreads();
    if (t < 224) {
        int r = t / 56, k = t - r * 56;
        float sr = 0.f, si = 0.f; int idx = 0;
        for (int j = 0; j < 56; ++j) {
            float2 a = sx[r][j];
            float2 tw = stw[idx];
            sr = fmaf(a.x, tw.x, fmaf(-a.y, tw.y, sr));
            si = fmaf(a.x, tw.y, fmaf( a.y, tw.x, si));
            idx += k; if (idx >= 56) idx -= 56;
        }
        specS[bg * P_ + (r0 + r) * 56 + k] = make_float2(sr, si);
        float amp = sqrtf(sr * sr + si * si);
        int p = k * 56 + (r0 + r);               // kh*56 + kw
        atomicAdd(&sbins[lab_of(p)], amp);
    }
    __syncthreads();
    if (t < NB_) atomicAdd(&sums[bg * NB_ + t], sbins[t]);
}

// FC: pooled = sums/counts; att = leaky_relu(W_g pooled + b_g)
__global__ __launch_bounds__(256) void fc_kernel(const float* __restrict__ sums,
                                                 const float* __restrict__ fc_w,
                                                 const float* __restrict__ fc_b,
                                                 float* __restrict__ att) {
    int bg = blockIdx.x, g = bg & 3;
    __shared__ int   s_cnt[NB_];
    __shared__ float s_pool[NB_];
    int t = threadIdx.x;
    if (t < NB_) s_cnt[t] = 0;
    __syncthreads();
    for (int p = t; p < P_; p += 256) atomicAdd(&s_cnt[lab_of(p)], 1);
    __syncthreads();
    if (t < NB_) s_pool[t] = sums[bg * NB_ + t] / (float)s_cnt[t];
    __syncthreads();
    if (t < NB_) {
        float acc = fc_b[g * NB_ + t];
        const float* wrow = &fc_w[(g * NB_ + t) * NB_];
        for (int n = 0; n < NB_; ++n) acc += s_pool[n] * wrow[n];
        att[bg * NB_ + t] = acc >= 0.f ? acc : 0.01f * acc;
    }
}

// I1: A[bg][h][kw] = sum_kh specS[bg][kw][kh] * att[lab(kh,kw)] * e^{+2pi i kh h/56}
// block = (bg, 4 rows kw). Map: r=t&3 (kw), k=t>>2 (h).
__global__ __launch_bounds__(256) void dft_i1(const float2* __restrict__ specS,
                                              const float* __restrict__ att,
                                              float2* __restrict__ A_s) {
    int blk = blockIdx.x, bg = blk / 14, r0 = (blk - bg * 14) * 4;
    __shared__ float2 sx[4][57];
    __shared__ float2 stw[56];
    __shared__ float  s_att[NB_];
    int t = threadIdx.x;
    if (t < 56) { float a = TWO_PI * (float)t / 56.f; stw[t] = make_float2(cosf(a), sinf(a)); }
    if (t < NB_) s_att[t] = att[bg * NB_ + t];
    __syncthreads();
    if (t < 224) {
        int row = t / 56, j = t - row * 56;      // (kw=r0+row, kh=j)
        float2 v = specS[bg * P_ + (r0 + row) * 56 + j];
        float a = s_att[lab_of(j * 56 + (r0 + row))];
        sx[row][j] = make_float2(v.x * a, v.y * a);
    }
    __syncthreads();
    if (t < 224) {
        int r = t & 3, k = t >> 2;               // kw offset r, h = k
        float sr = 0.f, si = 0.f; int idx = 0;
        for (int j = 0; j < 56; ++j) {
            float2 a = sx[r][j];
            float2 tw = stw[idx];
            sr = fmaf(a.x, tw.x, fmaf(-a.y, tw.y, sr));
            si = fmaf(a.x, tw.y, fmaf( a.y, tw.x, si));
            idx += k; if (idx >= 56) idx -= 56;
        }
        A_s[bg * P_ + k * 56 + (r0 + r)] = make_float2(sr, si);
    }
}

// I2: nf[bg][h][w] = (1/P) Re sum_kw A[bg][h][kw] e^{+2pi i kw w/56}; plane min/max.
// block = (bg, 4 rows h). Map: r=t/56 (h row), k=t%56 (w). Coalesced writes.
__global__ __launch_bounds__(256) void dft_i2(const float2* __restrict__ A_s,
                                              float* __restrict__ nf,
                                              unsigned* __restrict__ mnmx) {
    int blk = blockIdx.x, bg = blk / 14, r0 = (blk - bg * 14) * 4;
    __shared__ float2 sx[4][57];
    __shared__ float2 stw[56];
    __shared__ float  s_mn[256], s_mx[256];
    int t = threadIdx.x;
    if (t < 56) { float a = TWO_PI * (float)t / 56.f; stw[t] = make_float2(cosf(a), sinf(a)); }
    if (t < 224) sx[t / 56][t % 56] = A_s[bg * P_ + (r0 + t / 56) * 56 + (t % 56)];
    __syncthreads();
    float lmn = INFINITY, lmx = -INFINITY;
    if (t < 224) {
        int r = t / 56, k = t - r * 56;
        float sr = 0.f; int idx = 0;
        for (int j = 0; j < 56; ++j) {
            float2 a = sx[r][j];
            float2 tw = stw[idx];
            sr = fmaf(a.x, tw.x, fmaf(-a.y, tw.y, sr));
            idx += k; if (idx >= 56) idx -= 56;
        }
        float v = sr * (1.0f / (float)P_);
        nf[bg * P_ + (r0 + r) * 56 + k] = v;
        lmn = v; lmx = v;
    }
    s_mn[t] = lmn; s_mx[t] = lmx;
    __syncthreads();
    for (int off = 128; off > 0; off >>= 1) {
        if (t < off) {
            s_mn[t] = fminf(s_mn[t], s_mn[t + off]);
            s_mx[t] = fmaxf(s_mx[t], s_mx[t + off]);
        }
        __syncthreads();
    }
    if (t == 0) {
        atomicMin(&mnmx[bg * 2 + 0], fkey(s_mn[0]));
        atomicMax(&mnmx[bg * 2 + 1], fkey(s_mx[0]));
    }
}

// Final: out = feature + gamma[c] * feature * attn_map, float4.
__global__ __launch_bounds__(256) void final_kernel(const float* __restrict__ feature,
                                                    const float* __restrict__ gamma,
                                                    const float* __restrict__ nf,
                                                    const unsigned* __restrict__ mnmx,
                                                    float* __restrict__ out) {
    int i = blockIdx.x * 256 + threadIdx.x;      // over N4_ (exact)
    int e = i << 2;
    int b = e / CP_;
    int rem = e - b * CP_;
    int c = rem / P_;
    int p = rem - c * P_;
    int bg = (b << 2) | (c >> 6);
    float mn = fdec(mnmx[bg * 2 + 0]);
    float mx = fdec(mnmx[bg * 2 + 1]);
    float inv = 1.0f / (mx - mn);
    float4 f = ((const float4*)feature)[i];
    float4 v = *(const float4*)&nf[bg * P_ + p];
    float gam = gamma[c];
    float4 o;
    o.x = f.x + gam * f.x * ((v.x - mn) * inv);
    o.y = f.y + gam * f.y * ((v.y - mn) * inv);
    o.z = f.z + gam * f.z * ((v.z - mn) * inv);
    o.w = f.w + gam * f.w * ((v.w - mn) * inv);
    ((float4*)out)[i] = o;
}

extern "C" void kernel_launch(void* const* d_in, const int* in_sizes, int n_in,
                              void* d_out, int out_size, void* d_ws, size_t ws_size,
                              hipStream_t stream) {
    const float* feature = (const float*)d_in[0];
    const float* gamma   = (const float*)d_in[1];
    const float* fc_w    = (const float*)d_in[2];
    const float* fc_b    = (const float*)d_in[3];

    float* ws = (float*)d_ws;
    float*    comp  = ws;                         // 401408
    float2*   tmpF  = (float2*)(ws + 401408);     // 401408 float2 (reused as A_s)
    float2*   specS = (float2*)(ws + 1204224);    // 401408 float2
    float*    nf    = ws + 2007040;               // 401408
    float*    sums  = ws + 2408448;               // 3712
    float*    att   = ws + 2412160;               // 3712
    unsigned* mnmx  = (unsigned*)(ws + 2415872);  // 256
    float2*   A_s   = tmpF;                       // reuse (tmpF dead after F2)
    float* out = (float*)d_out;

    init_kernel <<<1, 256, 0, stream>>>(sums, mnmx);
    comp_kernel <<<(BG_ * 784) / 256, 256, 0, stream>>>(feature, comp);
    dft_f1      <<<BG_ * 14, 256, 0, stream>>>(comp, tmpF);
    dft_f2      <<<BG_ * 14, 256, 0, stream>>>(tmpF, specS, sums);
    fc_kernel   <<<BG_, 256, 0, stream>>>(sums, fc_w, fc_b, att);
    dft_i1      <<<BG_ * 14, 256, 0, stream>>>(specS, att, A_s);
    dft_i2      <<<BG_ * 14, 256, 0, stream>>>(A_s, nf, mnmx);
    final_kernel<<<N4_ / 256, 256, 0, stream>>>(feature, gamma, nf, mnmx, out);
}

// Round 3
// 93.075 us; speedup vs baseline: 1.9505x; 1.0778x over previous
//
#include <hip/hip_runtime.h>
#include <math.h>

// Problem constants: B=32, C=256, H=W=56, group=4, d=1
constexpr int B_  = 32;
constexpr int C_  = 256;
constexpr int G_  = 4;
constexpr int K_  = 64;
constexpr int P_  = 3136;        // 56*56
constexpr int NB_ = 29;
constexpr int BG_ = 128;         // B*G
constexpr int CP_ = C_ * P_;
constexpr int N_  = B_ * CP_;
constexpr int N4_ = N_ / 4;
constexpr float TWO_PI = 6.283185307179586f;

// Radial bin label in RAW (unshifted) coords, p = kh*56 + kw.
__device__ __forceinline__ int lab_of(int p) {
    int h = p / 56, w = p - h * 56;
    int hh = ((h + 28) % 56) - 28;
    int ww = ((w + 28) % 56) - 28;
    int r2 = hh * hh + ww * ww;
    int rf = (int)sqrtf((float)r2);
    while ((rf + 1) * (rf + 1) <= r2) ++rf;
    while (rf * rf > r2) --rf;
    if (rf > 28) rf = 28;
    return rf;
}

// Ordered-uint key for float atomic min/max.
__device__ __forceinline__ unsigned fkey(float f) {
    unsigned u = __float_as_uint(f);
    return (u & 0x80000000u) ? ~u : (u | 0x80000000u);
}
__device__ __forceinline__ float fdec(unsigned k) {
    return (k & 0x80000000u) ? __uint_as_float(k ^ 0x80000000u) : __uint_as_float(~k);
}

// Fused comp + F1. One block per (bg, 4 rows). Each thread owns one pixel:
// register-reduce mean+max over the group's 64 channels (coalesced, 28 waves/CU
// of TLP on the big feature read), stash comp in LDS, then row-DFT:
//   tmpF[bg][kw][h] = sum_w comp[bg][h][w] e^{-2pi i w kw/56}
// First block of each plane also re-inits sums/mnmx (consumed only by later
// kernels -> no race; re-done every call -> deterministic).
__global__ __launch_bounds__(256) void comp_f1_kernel(const float* __restrict__ feature,
                                                      float2* __restrict__ tmpF,
                                                      float* __restrict__ sums,
                                                      unsigned* __restrict__ mnmx) {
    int blk = blockIdx.x, bg = blk / 14, rblk = blk - bg * 14, r0 = rblk * 4;
    int b = bg >> 2, g = bg & 3;
    int t = threadIdx.x;
    __shared__ float  sx[4][57];
    __shared__ float2 stw[56];
    if (rblk == 0) {
        if (t < NB_) sums[bg * NB_ + t] = 0.f;
        else if (t == NB_)     mnmx[bg * 2]     = 0xFFFFFFFFu;
        else if (t == NB_ + 1) mnmx[bg * 2 + 1] = 0u;
    }
    if (t < 56) { float a = -TWO_PI * (float)t / 56.f; stw[t] = make_float2(cosf(a), sinf(a)); }
    if (t < 224) {
        const float* base = feature + (b * C_ + g * K_) * P_ + r0 * 56 + t;
        float sum = 0.f, mx = -INFINITY;
#pragma unroll 8
        for (int k = 0; k < K_; ++k) {
            float v = base[k * P_];
            sum += v;
            mx = fmaxf(mx, v);
        }
        sx[t / 56][t % 56] = sum * (1.f / 64.f) + mx;
    }
    __syncthreads();
    if (t < 224) {
        int r = t & 3, k = t >> 2;
        float sr = 0.f, si = 0.f; int idx = 0;
        for (int j = 0; j < 56; ++j) {
            float v = sx[r][j];
            float2 tw = stw[idx];
            sr = fmaf(v, tw.x, sr); si = fmaf(v, tw.y, si);
            idx += k; if (idx >= 56) idx -= 56;
        }
        tmpF[bg * P_ + k * 56 + (r0 + r)] = make_float2(sr, si);
    }
}

// F2: specS[bg][kw][kh] = sum_h tmpF[bg][kw][h] e^{-2pi i h kh/56}; bin sums of |spec|.
__global__ __launch_bounds__(256) void dft_f2(const float2* __restrict__ tmpF,
                                              float2* __restrict__ specS,
                                              float* __restrict__ sums) {
    int blk = blockIdx.x, bg = blk / 14, r0 = (blk - bg * 14) * 4;
    __shared__ float2 sx[4][57];
    __shared__ float2 stw[56];
    __shared__ float  sbins[NB_];
    int t = threadIdx.x;
    if (t < 56) { float a = -TWO_PI * (float)t / 56.f; stw[t] = make_float2(cosf(a), sinf(a)); }
    if (t < NB_) sbins[t] = 0.f;
    if (t < 224) sx[t / 56][t % 56] = tmpF[bg * P_ + (r0 + t / 56) * 56 + (t % 56)];
    __syncthreads();
    if (t < 224) {
        int r = t / 56, k = t - r * 56;
        float sr = 0.f, si = 0.f; int idx = 0;
        for (int j = 0; j < 56; ++j) {
            float2 a = sx[r][j];
            float2 tw = stw[idx];
            sr = fmaf(a.x, tw.x, fmaf(-a.y, tw.y, sr));
            si = fmaf(a.x, tw.y, fmaf( a.y, tw.x, si));
            idx += k; if (idx >= 56) idx -= 56;
        }
        specS[bg * P_ + (r0 + r) * 56 + k] = make_float2(sr, si);
        float amp = sqrtf(sr * sr + si * si);
        int p = k * 56 + (r0 + r);               // kh*56 + kw
        atomicAdd(&sbins[lab_of(p)], amp);
    }
    __syncthreads();
    if (t < NB_) atomicAdd(&sums[bg * NB_ + t], sbins[t]);
}

// FC: pooled = sums/counts; att = leaky_relu(W_g pooled + b_g)
__global__ __launch_bounds__(256) void fc_kernel(const float* __restrict__ sums,
                                                 const float* __restrict__ fc_w,
                                                 const float* __restrict__ fc_b,
                                                 float* __restrict__ att) {
    int bg = blockIdx.x, g = bg & 3;
    __shared__ int   s_cnt[NB_];
    __shared__ float s_pool[NB_];
    int t = threadIdx.x;
    if (t < NB_) s_cnt[t] = 0;
    __syncthreads();
    for (int p = t; p < P_; p += 256) atomicAdd(&s_cnt[lab_of(p)], 1);
    __syncthreads();
    if (t < NB_) s_pool[t] = sums[bg * NB_ + t] / (float)s_cnt[t];
    __syncthreads();
    if (t < NB_) {
        float acc = fc_b[g * NB_ + t];
        const float* wrow = &fc_w[(g * NB_ + t) * NB_];
        for (int n = 0; n < NB_; ++n) acc += s_pool[n] * wrow[n];
        att[bg * NB_ + t] = acc >= 0.f ? acc : 0.01f * acc;
    }
}

// I1: A[bg][h][kw] = sum_kh specS[bg][kw][kh] * att[lab(kh,kw)] * e^{+2pi i kh h/56}
__global__ __launch_bounds__(256) void dft_i1(const float2* __restrict__ specS,
                                              const float* __restrict__ att,
                                              float2* __restrict__ A_s) {
    int blk = blockIdx.x, bg = blk / 14, r0 = (blk - bg * 14) * 4;
    __shared__ float2 sx[4][57];
    __shared__ float2 stw[56];
    __shared__ float  s_att[NB_];
    int t = threadIdx.x;
    if (t < 56) { float a = TWO_PI * (float)t / 56.f; stw[t] = make_float2(cosf(a), sinf(a)); }
    if (t < NB_) s_att[t] = att[bg * NB_ + t];
    __syncthreads();
    if (t < 224) {
        int row = t / 56, j = t - row * 56;      // (kw=r0+row, kh=j)
        float2 v = specS[bg * P_ + (r0 + row) * 56 + j];
        float a = s_att[lab_of(j * 56 + (r0 + row))];
        sx[row][j] = make_float2(v.x * a, v.y * a);
    }
    __syncthreads();
    if (t < 224) {
        int r = t & 3, k = t >> 2;               // kw offset r, h = k
        float sr = 0.f, si = 0.f; int idx = 0;
        for (int j = 0; j < 56; ++j) {
            float2 a = sx[r][j];
            float2 tw = stw[idx];
            sr = fmaf(a.x, tw.x, fmaf(-a.y, tw.y, sr));
            si = fmaf(a.x, tw.y, fmaf( a.y, tw.x, si));
            idx += k; if (idx >= 56) idx -= 56;
        }
        A_s[bg * P_ + k * 56 + (r0 + r)] = make_float2(sr, si);
    }
}

// I2: nf[bg][h][w] = (1/P) Re sum_kw A[bg][h][kw] e^{+2pi i kw w/56}; plane min/max.
__global__ __launch_bounds__(256) void dft_i2(const float2* __restrict__ A_s,
                                              float* __restrict__ nf,
                                              unsigned* __restrict__ mnmx) {
    int blk = blockIdx.x, bg = blk / 14, r0 = (blk - bg * 14) * 4;
    __shared__ float2 sx[4][57];
    __shared__ float2 stw[56];
    __shared__ float  s_mn[256], s_mx[256];
    int t = threadIdx.x;
    if (t < 56) { float a = TWO_PI * (float)t / 56.f; stw[t] = make_float2(cosf(a), sinf(a)); }
    if (t < 224) sx[t / 56][t % 56] = A_s[bg * P_ + (r0 + t / 56) * 56 + (t % 56)];
    __syncthreads();
    float lmn = INFINITY, lmx = -INFINITY;
    if (t < 224) {
        int r = t / 56, k = t - r * 56;
        float sr = 0.f; int idx = 0;
        for (int j = 0; j < 56; ++j) {
            float2 a = sx[r][j];
            float2 tw = stw[idx];
            sr = fmaf(a.x, tw.x, fmaf(-a.y, tw.y, sr));
            idx += k; if (idx >= 56) idx -= 56;
        }
        float v = sr * (1.0f / (float)P_);
        nf[bg * P_ + (r0 + r) * 56 + k] = v;
        lmn = v; lmx = v;
    }
    s_mn[t] = lmn; s_mx[t] = lmx;
    __syncthreads();
    for (int off = 128; off > 0; off >>= 1) {
        if (t < off) {
            s_mn[t] = fminf(s_mn[t], s_mn[t + off]);
            s_mx[t] = fmaxf(s_mx[t], s_mx[t + off]);
        }
        __syncthreads();
    }
    if (t == 0) {
        atomicMin(&mnmx[bg * 2 + 0], fkey(s_mn[0]));
        atomicMax(&mnmx[bg * 2 + 1], fkey(s_mx[0]));
    }
}

// Final: out = feature + gamma[c] * feature * attn_map, float4.
__global__ __launch_bounds__(256) void final_kernel(const float* __restrict__ feature,
                                                    const float* __restrict__ gamma,
                                                    const float* __restrict__ nf,
                                                    const unsigned* __restrict__ mnmx,
                                                    float* __restrict__ out) {
    int i = blockIdx.x * 256 + threadIdx.x;      // over N4_ (exact)
    int b = i / (C_ * 784);
    int rem = i - b * (C_ * 784);
    int c = rem / 784;
    int p4 = rem - c * 784;
    int bg = (b << 2) | (c >> 6);
    float mn = fdec(mnmx[bg * 2 + 0]);
    float mx = fdec(mnmx[bg * 2 + 1]);
    float inv = 1.0f / (mx - mn);
    float4 f = ((const float4*)feature)[i];
    float4 v = ((const float4*)nf)[bg * 784 + p4];
    float gam = gamma[c];
    float4 o;
    o.x = f.x + gam * f.x * ((v.x - mn) * inv);
    o.y = f.y + gam * f.y * ((v.y - mn) * inv);
    o.z = f.z + gam * f.z * ((v.z - mn) * inv);
    o.w = f.w + gam * f.w * ((v.w - mn) * inv);
    ((float4*)out)[i] = o;
}

extern "C" void kernel_launch(void* const* d_in, const int* in_sizes, int n_in,
                              void* d_out, int out_size, void* d_ws, size_t ws_size,
                              hipStream_t stream) {
    const float* feature = (const float*)d_in[0];
    const float* gamma   = (const float*)d_in[1];
    const float* fc_w    = (const float*)d_in[2];
    const float* fc_b    = (const float*)d_in[3];

    float* ws = (float*)d_ws;
    float2*   tmpF  = (float2*)ws;                // 401408 float2 (reused as A_s)
    float2*   specS = (float2*)(ws + 802816);     // 401408 float2
    float*    nf    = ws + 1605632;               // 401408
    float*    sums  = ws + 2007040;               // 3712
    float*    att   = ws + 2010752;               // 3712
    unsigned* mnmx  = (unsigned*)(ws + 2014464);  // 256
    float2*   A_s   = tmpF;                       // reuse (tmpF dead after F2)
    float* out = (float*)d_out;

    comp_f1_kernel<<<BG_ * 14, 256, 0, stream>>>(feature, tmpF, sums, mnmx);
    dft_f2        <<<BG_ * 14, 256, 0, stream>>>(tmpF, specS, sums);
    fc_kernel     <<<BG_, 256, 0, stream>>>(sums, fc_w, fc_b, att);
    dft_i1        <<<BG_ * 14, 256, 0, stream>>>(specS, att, A_s);
    dft_i2        <<<BG_ * 14, 256, 0, stream>>>(A_s, nf, mnmx);
    final_kernel  <<<N4_ / 256, 256, 0, stream>>>(feature, gamma, nf, mnmx, out);
}